// Round 1
// 970.518 us; speedup vs baseline: 1.1281x; 1.1281x over previous
//
#include <hip/hip_runtime.h>
#include <stdint.h>

#define SEQ 2048
#define BATCH 2
#define NH 16
#define DKH 64
#define DM 1024
#define DFF 4096
#define MTOT (BATCH*SEQ)   // 4096 rows

typedef __attribute__((ext_vector_type(8))) short bf16x8;   // 8 bf16 in 4 VGPRs
typedef __attribute__((ext_vector_type(4))) float f32x4;

__device__ __forceinline__ unsigned short f2bf(float f) {
  union { float f; unsigned u; } c; c.f = f;
  return (unsigned short)((c.u + 0x7fffu + ((c.u >> 16) & 1u)) >> 16);  // RNE
}

// async global->LDS, 16B per lane; LDS dest must be wave-uniform base + lane*16
__device__ __forceinline__ void gload_lds16(const void* g, void* l) {
  __builtin_amdgcn_global_load_lds((__attribute__((address_space(1))) unsigned int*)g,
                                   (__attribute__((address_space(3))) unsigned int*)l,
                                   16, 0, 0);
}

// ---------------- prep kernels ----------------

__global__ __launch_bounds__(256) void conv_bf16(const float* __restrict__ X,
                                                 unsigned short* __restrict__ O, int n) {
  const int i = blockIdx.x * 256 + threadIdx.x;
  const int idx = i * 4;
  if (idx >= n) return;
  const float4 f = *(const float4*)(X + idx);
  ushort4 u; u.x = f2bf(f.x); u.y = f2bf(f.y); u.z = f2bf(f.z); u.w = f2bf(f.w);
  *(ushort4*)(O + idx) = u;
}

// W (K x N fp32, row-major) -> Wt (N x K bf16, row-major)  [B^T layout for gemm]
__global__ __launch_bounds__(256) void trans_conv(const float* __restrict__ W,
                                                  unsigned short* __restrict__ Wt,
                                                  int K, int N) {
  __shared__ float t[32][33];
  const int n0 = blockIdx.x * 32, k0 = blockIdx.y * 32;
  const int tx = threadIdx.x & 31, ty = threadIdx.x >> 5;  // 32 x 8
#pragma unroll
  for (int i = 0; i < 4; ++i)
    t[ty + i * 8][tx] = W[(long)(k0 + ty + i * 8) * N + n0 + tx];
  __syncthreads();
#pragma unroll
  for (int i = 0; i < 4; ++i)
    Wt[(long)(n0 + ty + i * 8) * K + k0 + tx] = f2bf(t[tx][ty + i * 8]);
}

__global__ __launch_bounds__(256) void concat3(const float* __restrict__ a,
                                               const float* __restrict__ b,
                                               const float* __restrict__ c,
                                               float* __restrict__ o) {
  const int i = blockIdx.x * 256 + threadIdx.x;  // grid 12 -> 3072
  o[i] = i < 1024 ? a[i] : (i < 2048 ? b[i - 1024] : c[i - 2048]);
}

// ---------------- generic bf16 GEMM: C[m][n] = sum_k A[m][k] * Bt[n][k] ----------------
// BK=64, LDS [slab(2)][row(128)][32] per matrix per k-segment.
// EPI: 0 = bf16 store (+bias), 2 = fp32 store + bias + resid,
//      3 = bf16 store of exact GELU(acc + bias), 4 = fused-QKV split epilogue
// KS: in-block split-K (1 or 2); KS=2 -> 512 threads, fp32 combine through LDS.
template <int EPI, int KS>
__global__ __launch_bounds__(256 * KS) void gemm_bt(
    const unsigned short* __restrict__ A, const unsigned short* __restrict__ Bt,
    float* __restrict__ Cf, unsigned short* __restrict__ Cbf,
    const float* __restrict__ bias, const float* __restrict__ resid,
    unsigned short* __restrict__ Vt,
    int M, int N, int K, int lda, int ldb, int ldc) {
  (void)M; (void)N;
  __shared__ unsigned short ldsAB[KS * 2 * 128 * 64];  // per seg: A(16KB) + B(16KB)

  const int tid = threadIdx.x;
  const int ws = tid >> 8;          // k-segment
  const int t2 = tid & 255;
  const int lane = tid & 63;
  const int w4 = (tid >> 6) & 3;    // wave within segment
  const int quad = lane >> 4, l16 = lane & 15;
  const int wm = (w4 >> 1) * 64, wn = (w4 & 1) * 64;
  const long tileM = (long)blockIdx.x * 128;
  const long tileN = (long)blockIdx.y * 128;

  unsigned short* ldsA = ldsAB + ws * 16384;
  unsigned short* ldsB = ldsA + 8192;
  const int kLen = K / KS;
  const int kBase = ws * kLen;

  const unsigned short* aS[4];
  const unsigned short* bS[4];
  int dOff[4];
#pragma unroll
  for (int it = 0; it < 4; ++it) {
    const int c = it * 256 + t2;
    const int slab = c >> 9, row = (c >> 2) & 127, q = c & 3;
    aS[it] = A  + (tileM + row) * (long)lda + kBase + slab * 32 + q * 8;
    bS[it] = Bt + (tileN + row) * (long)ldb + kBase + slab * 32 + q * 8;
    dOff[it] = c * 8;
  }

  f32x4 acc[4][4];
#pragma unroll
  for (int i = 0; i < 4; ++i)
#pragma unroll
    for (int j = 0; j < 4; ++j)
#pragma unroll
      for (int r = 0; r < 4; ++r) acc[i][j][r] = 0.f;

  for (int k0 = 0; k0 < kLen; k0 += 64) {
    __syncthreads();
#pragma unroll
    for (int it = 0; it < 4; ++it) {
      gload_lds16(aS[it] + k0, ldsA + dOff[it]);
      gload_lds16(bS[it] + k0, ldsB + dOff[it]);
    }
    __syncthreads();
#pragma unroll
    for (int s = 0; s < 2; ++s) {
      bf16x8 aF[4], bF[4];
#pragma unroll
      for (int i = 0; i < 4; ++i)
        aF[i] = *(const bf16x8*)&ldsA[(s * 128 + wm + i * 16 + l16) * 32 + quad * 8];
#pragma unroll
      for (int j = 0; j < 4; ++j)
        bF[j] = *(const bf16x8*)&ldsB[(s * 128 + wn + j * 16 + l16) * 32 + quad * 8];
#pragma unroll
      for (int i = 0; i < 4; ++i)
#pragma unroll
        for (int j = 0; j < 4; ++j)
          acc[i][j] = __builtin_amdgcn_mfma_f32_16x16x32_bf16(aF[i], bF[j], acc[i][j], 0, 0, 0);
    }
  }

  if constexpr (KS == 2) {
    __syncthreads();  // last-iter ds_reads done before reusing LDS as fp32 combine buf
    float* ldsF = (float*)ldsAB;  // 128x128 fp32 = 64KB = all of ldsAB
    if (ws == 1) {
#pragma unroll
      for (int i = 0; i < 4; ++i)
#pragma unroll
        for (int j = 0; j < 4; ++j)
#pragma unroll
          for (int r = 0; r < 4; ++r)
            ldsF[(wm + i * 16 + quad * 4 + r) * 128 + wn + j * 16 + l16] = acc[i][j][r];
    }
    __syncthreads();
    if (ws == 1) return;
#pragma unroll
    for (int i = 0; i < 4; ++i)
#pragma unroll
      for (int j = 0; j < 4; ++j)
#pragma unroll
        for (int r = 0; r < 4; ++r)
          acc[i][j][r] += ldsF[(wm + i * 16 + quad * 4 + r) * 128 + wn + j * 16 + l16];
  }

#pragma unroll
  for (int i = 0; i < 4; ++i) {
    const long mb = tileM + wm + i * 16 + quad * 4;
#pragma unroll
    for (int j = 0; j < 4; ++j) {
      const long n = tileN + wn + j * 16 + l16;
      const float bv = bias[n];
      if (EPI == 4) {
        if (n < 2048) {  // Q or K (Kbf is contiguous after Qbf in workspace)
          unsigned short* dst = Cbf + (n >> 10) * ((long)MTOT * DM);
          const int col = (int)n & 1023;
#pragma unroll
          for (int r = 0; r < 4; ++r)
            dst[(mb + r) * DM + col] = f2bf(acc[i][j][r] + bv);
        } else {         // V -> per-head transposed Vt[z][d][s]
          const int nn = (int)n - 2048;
          const int bb2 = (int)(mb >> 11), s = (int)(mb & 2047);
          const int zz = bb2 * 16 + (nn >> 6);
          ushort4 u;
          u.x = f2bf(acc[i][j][0] + bv); u.y = f2bf(acc[i][j][1] + bv);
          u.z = f2bf(acc[i][j][2] + bv); u.w = f2bf(acc[i][j][3] + bv);
          *(ushort4*)&Vt[((long)zz * DKH + (nn & 63)) * SEQ + s] = u;
        }
      } else {
#pragma unroll
        for (int r = 0; r < 4; ++r) {
          const long m = mb + r;
          const long idx = m * ldc + n;
          const float v = acc[i][j][r];
          if (EPI == 0) {
            Cbf[idx] = f2bf(v + bv);
          } else if (EPI == 2) {
            Cf[idx] = v + bv + resid[idx];
          } else {
            const float tt = v + bv;
            Cbf[idx] = f2bf(0.5f * tt * (1.f + erff(tt * 0.70710678118654752f)));
          }
        }
      }
    }
  }
}

// ---------------- merged attention ----------------
// sweep1: per-row (max, sumexp) of S = QK^T/8 via per-lane online accumulation
// sweep2: attn = softmax(S) written fp32 + ctx = attn @ V
// grid (SEQ/128, 1, BATCH*NH), block 256; LDS 80KB -> 2 blocks/CU
__device__ __forceinline__ void stage_k128(const unsigned short* __restrict__ gbase,
                                           unsigned short* lds, int tid) {
#pragma unroll
  for (int it = 0; it < 4; ++it) {
    const int c = it * 256 + tid;
    const int slab = c >> 9, row = (c >> 2) & 127, q = c & 3;
    gload_lds16(gbase + (long)row * DM + slab * 32 + q * 8, lds + c * 8);
  }
}
__device__ __forceinline__ void stage_v64(const unsigned short* __restrict__ gbase,
                                          unsigned short* lds, int tid) {
#pragma unroll
  for (int it = 0; it < 4; ++it) {
    const int c = it * 256 + tid;
    const int slab = c >> 8, row = (c >> 2) & 63, q = c & 3;
    gload_lds16(gbase + (long)row * SEQ + slab * 32 + q * 8, lds + c * 8);
  }
}

__global__ __launch_bounds__(256) void attn_all(const unsigned short* __restrict__ Qbf,
                                                const unsigned short* __restrict__ Kbf,
                                                const unsigned short* __restrict__ Vt,
                                                float* __restrict__ attn,
                                                unsigned short* __restrict__ Ctx) {
  const int z = blockIdx.z, b = z >> 4, h = z & 15;
  const int m0 = blockIdx.x * 128;

  __shared__ unsigned short ldsQ[2 * 128 * 32];  // 16 KB (K dbuf#1 after Q-hoist)
  __shared__ unsigned short ldsK[2 * 128 * 32];  // 16 KB (K dbuf#0)
  __shared__ unsigned short ldsV[4 * 64 * 32];   // 16 KB  [slab][d][32]
  __shared__ unsigned short ldsP[4 * 128 * 32];  // 32 KB  [slab][row][32] (sm alias)

  const int tid = threadIdx.x;
  const int lane = tid & 63, wave = tid >> 6;
  const int quad = lane >> 4, l16 = lane & 15;
  const int wm = (wave >> 1) * 64, wn = (wave & 1) * 64;
  const int wn2 = (wave & 1) * 32;

  const unsigned short* Qbase = Qbf + ((long)(b * SEQ + m0)) * DM + h * DKH;
  const unsigned short* Kz = Kbf + ((long)b * SEQ) * DM + h * DKH;
  const unsigned short* Vz = Vt + (long)z * DKH * SEQ;

  // stage Q strip + K tile 0
  stage_k128(Qbase, ldsQ, tid);
  stage_k128(Kz, ldsK, tid);
  __syncthreads();

  // hoist Q fragments to registers; ldsQ becomes K double-buffer slot 1
  bf16x8 qF[2][4];
#pragma unroll
  for (int s = 0; s < 2; ++s)
#pragma unroll
    for (int i = 0; i < 4; ++i)
      qF[s][i] = *(const bf16x8*)&ldsQ[(s * 128 + wm + i * 16 + l16) * 32 + quad * 8];
  __syncthreads();

  // ---- sweep 1: stats (per-lane online softmax over this lane's 4 cols/tile) ----
  float rm[4][4], rl[4][4];
#pragma unroll
  for (int i = 0; i < 4; ++i)
#pragma unroll
    for (int r = 0; r < 4; ++r) { rm[i][r] = -1e30f; rl[i][r] = 0.f; }

  for (int n = 0; n < 16; ++n) {
    if (n) __syncthreads();
    if (n < 15) stage_k128(Kz + (long)(n + 1) * 128 * DM, (n & 1) ? ldsK : ldsQ, tid);
    const unsigned short* kc = (n & 1) ? ldsQ : ldsK;

    f32x4 acc[4][4];
#pragma unroll
    for (int i = 0; i < 4; ++i)
#pragma unroll
      for (int j = 0; j < 4; ++j)
#pragma unroll
        for (int r = 0; r < 4; ++r) acc[i][j][r] = 0.f;
#pragma unroll
    for (int s = 0; s < 2; ++s) {
      bf16x8 bF[4];
#pragma unroll
      for (int j = 0; j < 4; ++j)
        bF[j] = *(const bf16x8*)&kc[(s * 128 + wn + j * 16 + l16) * 32 + quad * 8];
#pragma unroll
      for (int i = 0; i < 4; ++i)
#pragma unroll
        for (int j = 0; j < 4; ++j)
          acc[i][j] = __builtin_amdgcn_mfma_f32_16x16x32_bf16(qF[s][i], bF[j], acc[i][j], 0, 0, 0);
    }
#pragma unroll
    for (int i = 0; i < 4; ++i)
#pragma unroll
      for (int r = 0; r < 4; ++r) {
        const float v0 = acc[i][0][r] * 0.125f, v1 = acc[i][1][r] * 0.125f;
        const float v2 = acc[i][2][r] * 0.125f, v3 = acc[i][3][r] * 0.125f;
        const float tm = fmaxf(fmaxf(v0, v1), fmaxf(v2, v3));
        const float mn = fmaxf(rm[i][r], tm);
        rl[i][r] = rl[i][r] * __expf(rm[i][r] - mn) +
                   __expf(v0 - mn) + __expf(v1 - mn) + __expf(v2 - mn) + __expf(v3 - mn);
        rm[i][r] = mn;
      }
  }

  // butterfly merge across the 16 col-lanes
#pragma unroll
  for (int i = 0; i < 4; ++i)
#pragma unroll
    for (int r = 0; r < 4; ++r) {
      float m = rm[i][r], l = rl[i][r];
#pragma unroll
      for (int o = 1; o < 16; o <<= 1) {
        const float om = __shfl_xor(m, o), ol = __shfl_xor(l, o);
        const float mn = fmaxf(m, om);
        l = l * __expf(m - mn) + ol * __expf(om - mn);
        m = mn;
      }
      rm[i][r] = m; rl[i][r] = l;
    }

  // combine the two wn-halves per row through LDS (alias head of ldsP)
  float2* sm = (float2*)ldsP;
  if (l16 == 0) {
#pragma unroll
    for (int i = 0; i < 4; ++i)
#pragma unroll
      for (int r = 0; r < 4; ++r)
        sm[wave * 64 + i * 16 + quad * 4 + r] = make_float2(rm[i][r], rl[i][r]);
  }
  __syncthreads();
  float sM[4][4], sI[4][4];
#pragma unroll
  for (int i = 0; i < 4; ++i)
#pragma unroll
    for (int r = 0; r < 4; ++r) {
      const int rr = i * 16 + quad * 4 + r;
      const float2 A = sm[(wave & ~1) * 64 + rr];
      const float2 B = sm[((wave & ~1) + 1) * 64 + rr];
      const float M = fmaxf(A.x, B.x);
      const float Z = A.y * __expf(A.x - M) + B.y * __expf(B.x - M);
      sM[i][r] = M; sI[i][r] = 1.f / Z;
    }

  // ---- sweep 2: P write + PV ----
  f32x4 acc_o[4][2];
#pragma unroll
  for (int i = 0; i < 4; ++i)
#pragma unroll
    for (int j = 0; j < 2; ++j)
#pragma unroll
      for (int r = 0; r < 4; ++r) acc_o[i][j][r] = 0.f;

  stage_k128(Kz, ldsK, tid);  // restage tile 0
  __syncthreads();            // sm reads done by all waves + K0 staged

  for (int n = 0; n < 16; ++n) {
    if (n) __syncthreads();   // [A] prior PV reads of ldsP/ldsV done
    if (n < 15) stage_k128(Kz + (long)(n + 1) * 128 * DM, (n & 1) ? ldsK : ldsQ, tid);
    stage_v64(Vz + n * 128, ldsV, tid);
    const unsigned short* kc = (n & 1) ? ldsQ : ldsK;

    f32x4 acc[4][4];
#pragma unroll
    for (int i = 0; i < 4; ++i)
#pragma unroll
      for (int j = 0; j < 4; ++j)
#pragma unroll
        for (int r = 0; r < 4; ++r) acc[i][j][r] = 0.f;
    __builtin_amdgcn_s_setprio(1);
#pragma unroll
    for (int s = 0; s < 2; ++s) {
      bf16x8 bF[4];
#pragma unroll
      for (int j = 0; j < 4; ++j)
        bF[j] = *(const bf16x8*)&kc[(s * 128 + wn + j * 16 + l16) * 32 + quad * 8];
#pragma unroll
      for (int i = 0; i < 4; ++i)
#pragma unroll
        for (int j = 0; j < 4; ++j)
          acc[i][j] = __builtin_amdgcn_mfma_f32_16x16x32_bf16(qF[s][i], bF[j], acc[i][j], 0, 0, 0);
    }
    __builtin_amdgcn_s_setprio(0);

    // P = exp(S/8 - M) * invZ : fp32 attn (mandatory) + bf16 into ldsP (A-layout)
    float* attnBase = attn + (long)z * SEQ * SEQ + (long)m0 * SEQ + n * 128;
#pragma unroll
    for (int i = 0; i < 4; ++i)
#pragma unroll
      for (int r = 0; r < 4; ++r) {
        const int rowl = wm + i * 16 + quad * 4 + r;
        const float M = sM[i][r], I = sI[i][r];
#pragma unroll
        for (int j = 0; j < 4; ++j) {
          const int col = wn + j * 16 + l16;
          const float p = __expf(acc[i][j][r] * 0.125f - M) * I;
          attnBase[(long)rowl * SEQ + col] = p;
          ldsP[((col >> 5) * 128 + rowl) * 32 + (col & 31)] = f2bf(p);
        }
      }
    __syncthreads();  // [B] P visible; V(n) gloads drained

    __builtin_amdgcn_s_setprio(1);
#pragma unroll
    for (int slab = 0; slab < 4; ++slab) {
      bf16x8 aF[4], bF[2];
#pragma unroll
      for (int i = 0; i < 4; ++i)
        aF[i] = *(const bf16x8*)&ldsP[(slab * 128 + wm + i * 16 + l16) * 32 + quad * 8];
#pragma unroll
      for (int j = 0; j < 2; ++j)
        bF[j] = *(const bf16x8*)&ldsV[(slab * 64 + wn2 + j * 16 + l16) * 32 + quad * 8];
#pragma unroll
      for (int i = 0; i < 4; ++i)
#pragma unroll
        for (int j = 0; j < 2; ++j)
          acc_o[i][j] = __builtin_amdgcn_mfma_f32_16x16x32_bf16(aF[i], bF[j], acc_o[i][j], 0, 0, 0);
    }
    __builtin_amdgcn_s_setprio(0);
  }

  // epilogue: ctx bf16 (rows interleaved back to [B*S][DM])
#pragma unroll
  for (int i = 0; i < 4; ++i)
#pragma unroll
    for (int j = 0; j < 2; ++j) {
      const int d = h * DKH + wn2 + j * 16 + l16;
#pragma unroll
      for (int r = 0; r < 4; ++r) {
        const long m = (long)b * SEQ + m0 + wm + i * 16 + quad * 4 + r;
        Ctx[m * DM + d] = f2bf(acc_o[i][j][r]);
      }
    }
}

// ---------------- LayerNorm over rows of 1024 ----------------
__global__ __launch_bounds__(256) void layernorm_row(const float* __restrict__ Y,
                                                     const float* __restrict__ g,
                                                     const float* __restrict__ bb,
                                                     float* __restrict__ outF,
                                                     unsigned short* __restrict__ outBf) {
  const long row = blockIdx.x;
  const float* p = Y + row * DM;
  const int tid = threadIdx.x;
  const float4 v = *(const float4*)(p + tid * 4);
  float s = v.x + v.y + v.z + v.w;
  float ss = v.x * v.x + v.y * v.y + v.z * v.z + v.w * v.w;
#pragma unroll
  for (int o = 32; o > 0; o >>= 1) { s += __shfl_xor(s, o); ss += __shfl_xor(ss, o); }
  __shared__ float rs[4], rss[4];
  if ((tid & 63) == 0) { rs[tid >> 6] = s; rss[tid >> 6] = ss; }
  __syncthreads();
  s = rs[0] + rs[1] + rs[2] + rs[3];
  ss = rss[0] + rss[1] + rss[2] + rss[3];
  const float mu = s * (1.f / DM);
  const float var = ss * (1.f / DM) - mu * mu;
  const float rstd = rsqrtf(var + 1e-5f);
  const float4 gv = *(const float4*)(g + tid * 4);
  const float4 bv = *(const float4*)(bb + tid * 4);
  float4 o;
  o.x = (v.x - mu) * rstd * gv.x + bv.x;
  o.y = (v.y - mu) * rstd * gv.y + bv.y;
  o.z = (v.z - mu) * rstd * gv.z + bv.z;
  o.w = (v.w - mu) * rstd * gv.w + bv.w;
  *(float4*)(outF + row * DM + tid * 4) = o;
  if (outBf) {
    ushort4 u; u.x = f2bf(o.x); u.y = f2bf(o.y); u.z = f2bf(o.z); u.w = f2bf(o.w);
    *(ushort4*)(outBf + row * DM + tid * 4) = u;
  }
}

// ---------------- launch ----------------
extern "C" void kernel_launch(void* const* d_in, const int* in_sizes, int n_in,
                              void* d_out, int out_size, void* d_ws, size_t ws_size,
                              hipStream_t stream) {
  (void)in_sizes; (void)n_in; (void)out_size; (void)ws_size;
  const float* x  = (const float*)d_in[0];
  const float* Wq = (const float*)d_in[1];
  const float* bq = (const float*)d_in[2];
  const float* Wk = (const float*)d_in[3];
  const float* bk = (const float*)d_in[4];
  const float* Wv = (const float*)d_in[5];
  const float* bv = (const float*)d_in[6];
  const float* Wo = (const float*)d_in[7];
  const float* bo = (const float*)d_in[8];
  const float* g1 = (const float*)d_in[9];
  const float* b1 = (const float*)d_in[10];
  const float* W1 = (const float*)d_in[11];
  const float* bf1 = (const float*)d_in[12];
  const float* W2 = (const float*)d_in[13];
  const float* bf2 = (const float*)d_in[14];
  const float* g2 = (const float*)d_in[15];
  const float* b2 = (const float*)d_in[16];

  float* out  = (float*)d_out;
  float* attn = out + (long)MTOT * DM;   // (B,H,S,S) fp32 — written once, by attn_all

  // workspace layout (liveness-aliased), 96 MB total
  char* w = (char*)d_ws;
  const long MB = 1024L * 1024L;
  unsigned short* Wqkvt = (unsigned short*)(w + 0 * MB);   // 6 MB [Wq|Wk|Wv]^T
  unsigned short* Wot   = (unsigned short*)(w + 6 * MB);   // 2 MB
  unsigned short* W1t   = (unsigned short*)(w + 8 * MB);   // 8 MB
  unsigned short* W2t   = (unsigned short*)(w + 16 * MB);  // 8 MB
  unsigned short* xbf   = (unsigned short*)(w + 24 * MB);  // 8 MB, reused as hbf
  unsigned short* hbf   = xbf;
  unsigned short* Qbf   = (unsigned short*)(w + 32 * MB);  // 8 MB ┐ Kbf MUST follow Qbf
  unsigned short* Kbf   = (unsigned short*)(w + 40 * MB);  // 8 MB │ (EPI4 relies on it)
  unsigned short* Vt    = (unsigned short*)(w + 48 * MB);  // 8 MB │ ffbf aliases 32..64 MB
  unsigned short* ctxbf = (unsigned short*)(w + 56 * MB);  // 8 MB ┘
  unsigned short* ffbf  = Qbf;                             // 32 MB alias (dead by FF1)
  float* bqkv = (float*)(w + 64 * MB);                     // 12 KB, dead before y written
  float* y    = (float*)(w + 64 * MB);                     // 16 MB (first write: Wo-gemm)
  float* h    = (float*)(w + 80 * MB);                     // 16 MB

  const dim3 blk(256), blk2(512);

  // prep
  conv_bf16<<<dim3(MTOT * DM / 1024), blk, 0, stream>>>(x, xbf, MTOT * DM);
  trans_conv<<<dim3(DM / 32, DM / 32), blk, 0, stream>>>(Wq, Wqkvt, DM, DM);
  trans_conv<<<dim3(DM / 32, DM / 32), blk, 0, stream>>>(Wk, Wqkvt + 1024 * 1024, DM, DM);
  trans_conv<<<dim3(DM / 32, DM / 32), blk, 0, stream>>>(Wv, Wqkvt + 2 * 1024 * 1024, DM, DM);
  trans_conv<<<dim3(DM / 32, DM / 32), blk, 0, stream>>>(Wo, Wot, DM, DM);
  trans_conv<<<dim3(DFF / 32, DM / 32), blk, 0, stream>>>(W1, W1t, DM, DFF);
  trans_conv<<<dim3(DM / 32, DFF / 32), blk, 0, stream>>>(W2, W2t, DFF, DM);
  concat3<<<dim3(12), blk, 0, stream>>>(bq, bk, bv, bqkv);

  // fused QKV projection: N=3072, V written directly per-head-transposed
  gemm_bt<4, 1><<<dim3(MTOT / 128, 3072 / 128), blk, 0, stream>>>(
      xbf, Wqkvt, nullptr, Qbf, bqkv, nullptr, Vt, MTOT, 3072, DM, DM, DM, DM);

  // merged attention (stats sweep + P-write + PV)
  attn_all<<<dim3(SEQ / 128, 1, BATCH * NH), blk, 0, stream>>>(Qbf, Kbf, Vt, attn, ctxbf);

  // attn_out = ctx @ Wo + bo + x  (fp32); split-K for occupancy (256 blocks)
  gemm_bt<2, 2><<<dim3(MTOT / 128, DM / 128), blk2, 0, stream>>>(
      ctxbf, Wot, y, nullptr, bo, x, nullptr, MTOT, DM, DM, DM, DM, DM);
  layernorm_row<<<dim3(MTOT), blk, 0, stream>>>(y, g1, b1, h, hbf);

  // FFN
  gemm_bt<3, 1><<<dim3(MTOT / 128, DFF / 128), blk, 0, stream>>>(
      hbf, W1t, nullptr, ffbf, bf1, nullptr, nullptr, MTOT, DFF, DM, DM, DM, DFF);
  gemm_bt<2, 2><<<dim3(MTOT / 128, DM / 128), blk2, 0, stream>>>(
      ffbf, W2t, y, nullptr, bf2, h, nullptr, MTOT, DM, DFF, DFF, DFF, DM);
  layernorm_row<<<dim3(MTOT), blk, 0, stream>>>(y, g2, b2, out, nullptr);
}

// Round 4
// 948.479 us; speedup vs baseline: 1.1544x; 1.0232x over previous
//
#include <hip/hip_runtime.h>
#include <stdint.h>

#define SEQ 2048
#define BATCH 2
#define NH 16
#define DKH 64
#define DM 1024
#define DFF 4096
#define MTOT (BATCH*SEQ)   // 4096 rows

typedef __attribute__((ext_vector_type(8))) short bf16x8;   // 8 bf16 in 4 VGPRs
typedef __attribute__((ext_vector_type(4))) float f32x4;

__device__ __forceinline__ unsigned short f2bf(float f) {
  union { float f; unsigned u; } c; c.f = f;
  return (unsigned short)((c.u + 0x7fffu + ((c.u >> 16) & 1u)) >> 16);  // RNE
}

// async global->LDS, 16B per lane; LDS dest must be wave-uniform base + lane*16
__device__ __forceinline__ void gload_lds16(const void* g, void* l) {
  __builtin_amdgcn_global_load_lds((__attribute__((address_space(1))) unsigned int*)g,
                                   (__attribute__((address_space(3))) unsigned int*)l,
                                   16, 0, 0);
}

// XOR swizzle (ushort units) for 16B slots within a 64B row: spreads same-parity
// rows across slots -> <=2-way LDS bank aliasing (free). Applied on the GLOBAL
// source for gload_lds staging (rule: swizzle both-sides-or-neither) and as an
// address-XOR on direct ds reads/writes.
__device__ __forceinline__ int swz8(int row) { return ((row >> 1) & 3) * 8; }

// ---------------- prep kernels ----------------

__global__ __launch_bounds__(256) void conv_bf16(const float* __restrict__ X,
                                                 unsigned short* __restrict__ O, int n) {
  const int i = blockIdx.x * 256 + threadIdx.x;
  const int idx = i * 4;
  if (idx >= n) return;
  const float4 f = *(const float4*)(X + idx);
  ushort4 u; u.x = f2bf(f.x); u.y = f2bf(f.y); u.z = f2bf(f.z); u.w = f2bf(f.w);
  *(ushort4*)(O + idx) = u;
}

// W (K x N fp32, row-major) -> Wt (N x K bf16, row-major)  [B^T layout for gemm]
__global__ __launch_bounds__(256) void trans_conv(const float* __restrict__ W,
                                                  unsigned short* __restrict__ Wt,
                                                  int K, int N) {
  __shared__ float t[32][33];
  const int n0 = blockIdx.x * 32, k0 = blockIdx.y * 32;
  const int tx = threadIdx.x & 31, ty = threadIdx.x >> 5;  // 32 x 8
#pragma unroll
  for (int i = 0; i < 4; ++i)
    t[ty + i * 8][tx] = W[(long)(k0 + ty + i * 8) * N + n0 + tx];
  __syncthreads();
#pragma unroll
  for (int i = 0; i < 4; ++i)
    Wt[(long)(n0 + ty + i * 8) * K + k0 + tx] = f2bf(t[tx][ty + i * 8]);
}

__global__ __launch_bounds__(256) void concat3(const float* __restrict__ a,
                                               const float* __restrict__ b,
                                               const float* __restrict__ c,
                                               float* __restrict__ o) {
  const int i = blockIdx.x * 256 + threadIdx.x;  // grid 12 -> 3072
  o[i] = i < 1024 ? a[i] : (i < 2048 ? b[i - 1024] : c[i - 2048]);
}

// ---------------- generic bf16 GEMM: C[m][n] = sum_k A[m][k] * Bt[n][k] ----------------
// BK=64, LDS [slab(2)][row(128)][32] per matrix per k-segment.
// EPI: 0 = bf16 store (+bias), 2 = fp32 store + bias + resid,
//      3 = bf16 store of exact GELU(acc + bias), 4 = fused-QKV split epilogue
// KS: in-block split-K (1 or 2); KS=2 -> 512 threads, fp32 combine through LDS.
template <int EPI, int KS>
__global__ __launch_bounds__(256 * KS) void gemm_bt(
    const unsigned short* __restrict__ A, const unsigned short* __restrict__ Bt,
    float* __restrict__ Cf, unsigned short* __restrict__ Cbf,
    const float* __restrict__ bias, const float* __restrict__ resid,
    unsigned short* __restrict__ Vt,
    int M, int N, int K, int lda, int ldb, int ldc) {
  (void)M; (void)N;
  __shared__ unsigned short ldsAB[KS * 2 * 128 * 64];  // per seg: A(16KB) + B(16KB)

  const int tid = threadIdx.x;
  const int ws = tid >> 8;          // k-segment
  const int t2 = tid & 255;
  const int lane = tid & 63;
  const int w4 = (tid >> 6) & 3;    // wave within segment
  const int quad = lane >> 4, l16 = lane & 15;
  const int wm = (w4 >> 1) * 64, wn = (w4 & 1) * 64;
  const long tileM = (long)blockIdx.x * 128;
  const long tileN = (long)blockIdx.y * 128;

  unsigned short* ldsA = ldsAB + ws * 16384;
  unsigned short* ldsB = ldsA + 8192;
  const int kLen = K / KS;
  const int kBase = ws * kLen;

  const unsigned short* aS[4];
  const unsigned short* bS[4];
  int dOff[4];
#pragma unroll
  for (int it = 0; it < 4; ++it) {
    const int c = it * 256 + t2;
    const int slab = c >> 9, row = (c >> 2) & 127, q = c & 3;
    aS[it] = A  + (tileM + row) * (long)lda + kBase + slab * 32 + q * 8;
    bS[it] = Bt + (tileN + row) * (long)ldb + kBase + slab * 32 + q * 8;
    dOff[it] = c * 8;
  }

  f32x4 acc[4][4];
#pragma unroll
  for (int i = 0; i < 4; ++i)
#pragma unroll
    for (int j = 0; j < 4; ++j)
#pragma unroll
      for (int r = 0; r < 4; ++r) acc[i][j][r] = 0.f;

  for (int k0 = 0; k0 < kLen; k0 += 64) {
    __syncthreads();
#pragma unroll
    for (int it = 0; it < 4; ++it) {
      gload_lds16(aS[it] + k0, ldsA + dOff[it]);
      gload_lds16(bS[it] + k0, ldsB + dOff[it]);
    }
    __syncthreads();
#pragma unroll
    for (int s = 0; s < 2; ++s) {
      bf16x8 aF[4], bF[4];
#pragma unroll
      for (int i = 0; i < 4; ++i)
        aF[i] = *(const bf16x8*)&ldsA[(s * 128 + wm + i * 16 + l16) * 32 + quad * 8];
#pragma unroll
      for (int j = 0; j < 4; ++j)
        bF[j] = *(const bf16x8*)&ldsB[(s * 128 + wn + j * 16 + l16) * 32 + quad * 8];
#pragma unroll
      for (int i = 0; i < 4; ++i)
#pragma unroll
        for (int j = 0; j < 4; ++j)
          acc[i][j] = __builtin_amdgcn_mfma_f32_16x16x32_bf16(aF[i], bF[j], acc[i][j], 0, 0, 0);
    }
  }

  if constexpr (KS == 2) {
    __syncthreads();  // last-iter ds_reads done before reusing LDS as fp32 combine buf
    float* ldsF = (float*)ldsAB;  // 128x128 fp32 = 64KB = all of ldsAB
    if (ws == 1) {
#pragma unroll
      for (int i = 0; i < 4; ++i)
#pragma unroll
        for (int j = 0; j < 4; ++j)
#pragma unroll
          for (int r = 0; r < 4; ++r)
            ldsF[(wm + i * 16 + quad * 4 + r) * 128 + wn + j * 16 + l16] = acc[i][j][r];
    }
    __syncthreads();
    if (ws == 1) return;
#pragma unroll
    for (int i = 0; i < 4; ++i)
#pragma unroll
      for (int j = 0; j < 4; ++j)
#pragma unroll
        for (int r = 0; r < 4; ++r)
          acc[i][j][r] += ldsF[(wm + i * 16 + quad * 4 + r) * 128 + wn + j * 16 + l16];
  }

#pragma unroll
  for (int i = 0; i < 4; ++i) {
    const long mb = tileM + wm + i * 16 + quad * 4;
#pragma unroll
    for (int j = 0; j < 4; ++j) {
      const long n = tileN + wn + j * 16 + l16;
      const float bv = bias[n];
      if (EPI == 4) {
        if (n < 2048) {  // Q or K (Kbf is contiguous after Qbf in workspace)
          unsigned short* dst = Cbf + (n >> 10) * ((long)MTOT * DM);
          const int col = (int)n & 1023;
#pragma unroll
          for (int r = 0; r < 4; ++r)
            dst[(mb + r) * DM + col] = f2bf(acc[i][j][r] + bv);
        } else {         // V -> per-head transposed Vt[z][d][s]
          const int nn = (int)n - 2048;
          const int bb2 = (int)(mb >> 11), s = (int)(mb & 2047);
          const int zz = bb2 * 16 + (nn >> 6);
          ushort4 u;
          u.x = f2bf(acc[i][j][0] + bv); u.y = f2bf(acc[i][j][1] + bv);
          u.z = f2bf(acc[i][j][2] + bv); u.w = f2bf(acc[i][j][3] + bv);
          *(ushort4*)&Vt[((long)zz * DKH + (nn & 63)) * SEQ + s] = u;
        }
      } else {
#pragma unroll
        for (int r = 0; r < 4; ++r) {
          const long m = mb + r;
          const long idx = m * ldc + n;
          const float v = acc[i][j][r];
          if (EPI == 0) {
            Cbf[idx] = f2bf(v + bv);
          } else if (EPI == 2) {
            Cf[idx] = v + bv + resid[idx];
          } else {
            const float tt = v + bv;
            Cbf[idx] = f2bf(0.5f * tt * (1.f + erff(tt * 0.70710678118654752f)));
          }
        }
      }
    }
  }
}

// ---------------- merged attention ----------------
// Swapped-operand QK^T: acc[i][j] = mfma(K_frag_j, Q_frag_i) so each lane's 4
// regs are 4 CONSECUTIVE k-cols of ONE q-row (row = wm+i*16+l16, cols =
// wn+j*16+quad*4+r). Enables float4 attn stores, ushort4 P LDS writes, and
// per-row (not per-element-group) online softmax.
// grid (SEQ/128, 1, BATCH*NH), block 256; LDS 80KB -> 2 blocks/CU
__device__ __forceinline__ void stage_k128(const unsigned short* __restrict__ gbase,
                                           unsigned short* lds, int tid) {
#pragma unroll
  for (int it = 0; it < 4; ++it) {
    const int c = it * 256 + tid;
    const int slab = c >> 9, row = (c >> 2) & 127, q = (c & 3) * 8;
    gload_lds16(gbase + (long)row * DM + slab * 32 + (q ^ swz8(row)), lds + c * 8);
  }
}
__device__ __forceinline__ void stage_v64(const unsigned short* __restrict__ gbase,
                                          unsigned short* lds, int tid) {
#pragma unroll
  for (int it = 0; it < 4; ++it) {
    const int c = it * 256 + tid;
    const int slab = c >> 8, row = (c >> 2) & 63, q = (c & 3) * 8;
    gload_lds16(gbase + (long)row * SEQ + slab * 32 + (q ^ swz8(row)), lds + c * 8);
  }
}

__global__ __launch_bounds__(256) void attn_all(const unsigned short* __restrict__ Qbf,
                                                const unsigned short* __restrict__ Kbf,
                                                const unsigned short* __restrict__ Vt,
                                                float* __restrict__ attn,
                                                unsigned short* __restrict__ Ctx) {
  const int z = blockIdx.z, b = z >> 4, h = z & 15;
  const int m0 = blockIdx.x * 128;

  __shared__ unsigned short ldsQ[2 * 128 * 32];  // 16 KB (K dbuf#1 after Q-hoist)
  __shared__ unsigned short ldsK[2 * 128 * 32];  // 16 KB (K dbuf#0)
  __shared__ unsigned short ldsV[4 * 64 * 32];   // 16 KB  [slab][d][32]
  __shared__ unsigned short ldsP[4 * 128 * 32];  // 32 KB  [slab][row][32] (sm alias)

  const int tid = threadIdx.x;
  const int lane = tid & 63, wave = tid >> 6;
  const int quad = lane >> 4, l16 = lane & 15;
  const int wm = (wave >> 1) * 64, wn = (wave & 1) * 64;
  const int wn2 = (wave & 1) * 32;

  const unsigned short* Qbase = Qbf + ((long)(b * SEQ + m0)) * DM + h * DKH;
  const unsigned short* Kz = Kbf + ((long)b * SEQ) * DM + h * DKH;
  const unsigned short* Vz = Vt + (long)z * DKH * SEQ;

  // stage Q strip + K tile 0 (both source-swizzled)
  stage_k128(Qbase, ldsQ, tid);
  stage_k128(Kz, ldsK, tid);
  __syncthreads();

  // hoist Q fragments to registers; ldsQ becomes K double-buffer slot 1
  bf16x8 qF[2][4];
#pragma unroll
  for (int s = 0; s < 2; ++s)
#pragma unroll
    for (int i = 0; i < 4; ++i) {
      const int row = wm + i * 16 + l16;
      qF[s][i] = *(const bf16x8*)&ldsQ[(s * 128 + row) * 32 + ((quad * 8) ^ swz8(row))];
    }
  __syncthreads();

  // ---- sweep 1: per-row online (max, sumexp); lane owns q-row wm+i*16+l16 ----
  float rm[4], rl[4];
#pragma unroll
  for (int i = 0; i < 4; ++i) { rm[i] = -1e30f; rl[i] = 0.f; }

  for (int n = 0; n < 16; ++n) {
    if (n) __syncthreads();
    if (n < 15) stage_k128(Kz + (long)(n + 1) * 128 * DM, (n & 1) ? ldsK : ldsQ, tid);
    const unsigned short* kc = (n & 1) ? ldsQ : ldsK;

    f32x4 acc[4][4];
#pragma unroll
    for (int i = 0; i < 4; ++i)
#pragma unroll
      for (int j = 0; j < 4; ++j)
#pragma unroll
        for (int r = 0; r < 4; ++r) acc[i][j][r] = 0.f;
    __builtin_amdgcn_s_setprio(1);
#pragma unroll
    for (int s = 0; s < 2; ++s) {
      bf16x8 bF[4];
#pragma unroll
      for (int j = 0; j < 4; ++j) {
        const int row = wn + j * 16 + l16;
        bF[j] = *(const bf16x8*)&kc[(s * 128 + row) * 32 + ((quad * 8) ^ swz8(row))];
      }
#pragma unroll
      for (int i = 0; i < 4; ++i)
#pragma unroll
        for (int j = 0; j < 4; ++j)
          acc[i][j] = __builtin_amdgcn_mfma_f32_16x16x32_bf16(bF[j], qF[s][i], acc[i][j], 0, 0, 0);
    }
    __builtin_amdgcn_s_setprio(0);

#pragma unroll
    for (int i = 0; i < 4; ++i) {
      float tm = acc[i][0][0];
#pragma unroll
      for (int j = 0; j < 4; ++j)
#pragma unroll
        for (int r = 0; r < 4; ++r) tm = fmaxf(tm, acc[i][j][r]);
      const float tms = tm * 0.125f;
      const float mn = fmaxf(rm[i], tms);
      float sum = 0.f;
#pragma unroll
      for (int j = 0; j < 4; ++j)
#pragma unroll
        for (int r = 0; r < 4; ++r)
          sum += __expf(fmaf(acc[i][j][r], 0.125f, -mn));
      rl[i] = rl[i] * __expf(rm[i] - mn) + sum;
      rm[i] = mn;
    }
  }

  // merge across the 4 quads (same q-row, disjoint k-chunks): 2 butterfly steps
#pragma unroll
  for (int i = 0; i < 4; ++i) {
    float m = rm[i], l = rl[i];
#pragma unroll
    for (int o = 16; o < 64; o <<= 1) {
      const float om = __shfl_xor(m, o), ol = __shfl_xor(l, o);
      const float mn = fmaxf(m, om);
      l = l * __expf(m - mn) + ol * __expf(om - mn);
      m = mn;
    }
    rm[i] = m; rl[i] = l;
  }

  // combine the two wn-halves per row through LDS (alias head of ldsP)
  float2* sm = (float2*)ldsP;
  if (quad == 0) {
#pragma unroll
    for (int i = 0; i < 4; ++i)
      sm[wave * 64 + i * 16 + l16] = make_float2(rm[i], rl[i]);
  }
  __syncthreads();
  float sM[4], sI[4];
#pragma unroll
  for (int i = 0; i < 4; ++i) {
    const int rr = i * 16 + l16;
    const float2 A = sm[(wave & ~1) * 64 + rr];
    const float2 B = sm[((wave & ~1) + 1) * 64 + rr];
    const float M = fmaxf(A.x, B.x);
    const float Z = A.y * __expf(A.x - M) + B.y * __expf(B.x - M);
    sM[i] = M; sI[i] = 1.f / Z;
  }

  // ---- sweep 2: P write + PV ----
  f32x4 acc_o[4][2];
#pragma unroll
  for (int i = 0; i < 4; ++i)
#pragma unroll
    for (int j = 0; j < 2; ++j)
#pragma unroll
      for (int r = 0; r < 4; ++r) acc_o[i][j][r] = 0.f;

  stage_k128(Kz, ldsK, tid);  // restage tile 0
  __syncthreads();            // sm reads done by all waves + K0 staged

  for (int n = 0; n < 16; ++n) {
    if (n) __syncthreads();   // [A] prior PV reads of ldsP/ldsV done
    if (n < 15) stage_k128(Kz + (long)(n + 1) * 128 * DM, (n & 1) ? ldsK : ldsQ, tid);
    stage_v64(Vz + n * 128, ldsV, tid);
    const unsigned short* kc = (n & 1) ? ldsQ : ldsK;

    f32x4 acc[4][4];
#pragma unroll
    for (int i = 0; i < 4; ++i)
#pragma unroll
      for (int j = 0; j < 4; ++j)
#pragma unroll
        for (int r = 0; r < 4; ++r) acc[i][j][r] = 0.f;
    __builtin_amdgcn_s_setprio(1);
#pragma unroll
    for (int s = 0; s < 2; ++s) {
      bf16x8 bF[4];
#pragma unroll
      for (int j = 0; j < 4; ++j) {
        const int row = wn + j * 16 + l16;
        bF[j] = *(const bf16x8*)&kc[(s * 128 + row) * 32 + ((quad * 8) ^ swz8(row))];
      }
#pragma unroll
      for (int i = 0; i < 4; ++i)
#pragma unroll
        for (int j = 0; j < 4; ++j)
          acc[i][j] = __builtin_amdgcn_mfma_f32_16x16x32_bf16(bF[j], qF[s][i], acc[i][j], 0, 0, 0);
    }
    __builtin_amdgcn_s_setprio(0);

    // P = exp(S/8 - M) * invZ : f32x4 nt store to attn + ushort4 into ldsP
    float* attnBase = attn + (long)z * SEQ * SEQ + (long)m0 * SEQ + n * 128;
#pragma unroll
    for (int i = 0; i < 4; ++i) {
      const int rowl = wm + i * 16 + l16;
      const float M = sM[i], I = sI[i];
#pragma unroll
      for (int j = 0; j < 4; ++j) {
        const int col = wn + j * 16 + quad * 4;
        f32x4 p4;
        p4[0] = __expf(fmaf(acc[i][j][0], 0.125f, -M)) * I;
        p4[1] = __expf(fmaf(acc[i][j][1], 0.125f, -M)) * I;
        p4[2] = __expf(fmaf(acc[i][j][2], 0.125f, -M)) * I;
        p4[3] = __expf(fmaf(acc[i][j][3], 0.125f, -M)) * I;
        __builtin_nontemporal_store(p4, (f32x4*)(attnBase + (long)rowl * SEQ + col));
        ushort4 u;
        u.x = f2bf(p4[0]); u.y = f2bf(p4[1]); u.z = f2bf(p4[2]); u.w = f2bf(p4[3]);
        const int uoff = ((col >> 5) * 128 + rowl) * 32 + ((col & 31) ^ swz8(rowl));
        *(ushort4*)&ldsP[uoff] = u;
      }
    }
    __syncthreads();  // [B] P visible; V(n)/K(n+1) gloads drained

    __builtin_amdgcn_s_setprio(1);
#pragma unroll
    for (int slab = 0; slab < 4; ++slab) {
      bf16x8 aF[4], bF[2];
#pragma unroll
      for (int i = 0; i < 4; ++i) {
        const int row = wm + i * 16 + l16;
        aF[i] = *(const bf16x8*)&ldsP[(slab * 128 + row) * 32 + ((quad * 8) ^ swz8(row))];
      }
#pragma unroll
      for (int j = 0; j < 2; ++j) {
        const int d = wn2 + j * 16 + l16;
        bF[j] = *(const bf16x8*)&ldsV[(slab * 64 + d) * 32 + ((quad * 8) ^ swz8(d))];
      }
#pragma unroll
      for (int i = 0; i < 4; ++i)
#pragma unroll
        for (int j = 0; j < 2; ++j)
          acc_o[i][j] = __builtin_amdgcn_mfma_f32_16x16x32_bf16(aF[i], bF[j], acc_o[i][j], 0, 0, 0);
    }
    __builtin_amdgcn_s_setprio(0);
  }

  // epilogue: ctx bf16 (rows interleaved back to [B*S][DM])
#pragma unroll
  for (int i = 0; i < 4; ++i)
#pragma unroll
    for (int j = 0; j < 2; ++j) {
      const int d = h * DKH + wn2 + j * 16 + l16;
#pragma unroll
      for (int r = 0; r < 4; ++r) {
        const long m = (long)b * SEQ + m0 + wm + i * 16 + quad * 4 + r;
        Ctx[m * DM + d] = f2bf(acc_o[i][j][r]);
      }
    }
}

// ---------------- LayerNorm over rows of 1024 ----------------
__global__ __launch_bounds__(256) void layernorm_row(const float* __restrict__ Y,
                                                     const float* __restrict__ g,
                                                     const float* __restrict__ bb,
                                                     float* __restrict__ outF,
                                                     unsigned short* __restrict__ outBf) {
  const long row = blockIdx.x;
  const float* p = Y + row * DM;
  const int tid = threadIdx.x;
  const float4 v = *(const float4*)(p + tid * 4);
  float s = v.x + v.y + v.z + v.w;
  float ss = v.x * v.x + v.y * v.y + v.z * v.z + v.w * v.w;
#pragma unroll
  for (int o = 32; o > 0; o >>= 1) { s += __shfl_xor(s, o); ss += __shfl_xor(ss, o); }
  __shared__ float rs[4], rss[4];
  if ((tid & 63) == 0) { rs[tid >> 6] = s; rss[tid >> 6] = ss; }
  __syncthreads();
  s = rs[0] + rs[1] + rs[2] + rs[3];
  ss = rss[0] + rss[1] + rss[2] + rss[3];
  const float mu = s * (1.f / DM);
  const float var = ss * (1.f / DM) - mu * mu;
  const float rstd = rsqrtf(var + 1e-5f);
  const float4 gv = *(const float4*)(g + tid * 4);
  const float4 bv = *(const float4*)(bb + tid * 4);
  float4 o;
  o.x = (v.x - mu) * rstd * gv.x + bv.x;
  o.y = (v.y - mu) * rstd * gv.y + bv.y;
  o.z = (v.z - mu) * rstd * gv.z + bv.z;
  o.w = (v.w - mu) * rstd * gv.w + bv.w;
  *(float4*)(outF + row * DM + tid * 4) = o;
  if (outBf) {
    ushort4 u; u.x = f2bf(o.x); u.y = f2bf(o.y); u.z = f2bf(o.z); u.w = f2bf(o.w);
    *(ushort4*)(outBf + row * DM + tid * 4) = u;
  }
}

// ---------------- launch ----------------
extern "C" void kernel_launch(void* const* d_in, const int* in_sizes, int n_in,
                              void* d_out, int out_size, void* d_ws, size_t ws_size,
                              hipStream_t stream) {
  (void)in_sizes; (void)n_in; (void)out_size; (void)ws_size;
  const float* x  = (const float*)d_in[0];
  const float* Wq = (const float*)d_in[1];
  const float* bq = (const float*)d_in[2];
  const float* Wk = (const float*)d_in[3];
  const float* bk = (const float*)d_in[4];
  const float* Wv = (const float*)d_in[5];
  const float* bv = (const float*)d_in[6];
  const float* Wo = (const float*)d_in[7];
  const float* bo = (const float*)d_in[8];
  const float* g1 = (const float*)d_in[9];
  const float* b1 = (const float*)d_in[10];
  const float* W1 = (const float*)d_in[11];
  const float* bf1 = (const float*)d_in[12];
  const float* W2 = (const float*)d_in[13];
  const float* bf2 = (const float*)d_in[14];
  const float* g2 = (const float*)d_in[15];
  const float* b2 = (const float*)d_in[16];

  float* out  = (float*)d_out;
  float* attn = out + (long)MTOT * DM;   // (B,H,S,S) fp32 — written once, by attn_all

  // workspace layout (liveness-aliased), 96 MB total
  char* w = (char*)d_ws;
  const long MB = 1024L * 1024L;
  unsigned short* Wqkvt = (unsigned short*)(w + 0 * MB);   // 6 MB [Wq|Wk|Wv]^T
  unsigned short* Wot   = (unsigned short*)(w + 6 * MB);   // 2 MB
  unsigned short* W1t   = (unsigned short*)(w + 8 * MB);   // 8 MB
  unsigned short* W2t   = (unsigned short*)(w + 16 * MB);  // 8 MB
  unsigned short* xbf   = (unsigned short*)(w + 24 * MB);  // 8 MB, reused as hbf
  unsigned short* hbf   = xbf;
  unsigned short* Qbf   = (unsigned short*)(w + 32 * MB);  // 8 MB ┐ Kbf MUST follow Qbf
  unsigned short* Kbf   = (unsigned short*)(w + 40 * MB);  // 8 MB │ (EPI4 relies on it)
  unsigned short* Vt    = (unsigned short*)(w + 48 * MB);  // 8 MB │ ffbf aliases 32..64 MB
  unsigned short* ctxbf = (unsigned short*)(w + 56 * MB);  // 8 MB ┘
  unsigned short* ffbf  = Qbf;                             // 32 MB alias (dead by FF1)
  float* bqkv = (float*)(w + 64 * MB);                     // 12 KB, dead before y written
  float* y    = (float*)(w + 64 * MB);                     // 16 MB (first write: Wo-gemm)
  float* h    = (float*)(w + 80 * MB);                     // 16 MB

  const dim3 blk(256), blk2(512);

  // prep
  conv_bf16<<<dim3(MTOT * DM / 1024), blk, 0, stream>>>(x, xbf, MTOT * DM);
  trans_conv<<<dim3(DM / 32, DM / 32), blk, 0, stream>>>(Wq, Wqkvt, DM, DM);
  trans_conv<<<dim3(DM / 32, DM / 32), blk, 0, stream>>>(Wk, Wqkvt + 1024 * 1024, DM, DM);
  trans_conv<<<dim3(DM / 32, DM / 32), blk, 0, stream>>>(Wv, Wqkvt + 2 * 1024 * 1024, DM, DM);
  trans_conv<<<dim3(DM / 32, DM / 32), blk, 0, stream>>>(Wo, Wot, DM, DM);
  trans_conv<<<dim3(DFF / 32, DM / 32), blk, 0, stream>>>(W1, W1t, DM, DFF);
  trans_conv<<<dim3(DM / 32, DFF / 32), blk, 0, stream>>>(W2, W2t, DFF, DM);
  concat3<<<dim3(12), blk, 0, stream>>>(bq, bk, bv, bqkv);

  // fused QKV projection: N=3072, V written directly per-head-transposed
  gemm_bt<4, 1><<<dim3(MTOT / 128, 3072 / 128), blk, 0, stream>>>(
      xbf, Wqkvt, nullptr, Qbf, bqkv, nullptr, Vt, MTOT, 3072, DM, DM, DM, DM);

  // merged attention (stats sweep + P-write + PV)
  attn_all<<<dim3(SEQ / 128, 1, BATCH * NH), blk, 0, stream>>>(Qbf, Kbf, Vt, attn, ctxbf);

  // attn_out = ctx @ Wo + bo + x  (fp32); split-K for occupancy
  gemm_bt<2, 2><<<dim3(MTOT / 128, DM / 128), blk2, 0, stream>>>(
      ctxbf, Wot, y, nullptr, bo, x, nullptr, MTOT, DM, DM, DM, DM, DM);
  layernorm_row<<<dim3(MTOT), blk, 0, stream>>>(y, g1, b1, h, hbf);

  // FFN
  gemm_bt<3, 1><<<dim3(MTOT / 128, DFF / 128), blk, 0, stream>>>(
      hbf, W1t, nullptr, ffbf, bf1, nullptr, nullptr, MTOT, DFF, DM, DM, DM, DFF);
  gemm_bt<2, 2><<<dim3(MTOT / 128, DM / 128), blk2, 0, stream>>>(
      ffbf, W2t, y, nullptr, bf2, h, nullptr, MTOT, DM, DFF, DFF, DFF, DM);
  layernorm_row<<<dim3(MTOT), blk, 0, stream>>>(y, g2, b2, out, nullptr);
}

// Round 5
// 928.128 us; speedup vs baseline: 1.1797x; 1.0219x over previous
//
#include <hip/hip_runtime.h>
#include <stdint.h>

#define SEQ 2048
#define BATCH 2
#define NH 16
#define DKH 64
#define DM 1024
#define DFF 4096
#define MTOT (BATCH*SEQ)   // 4096 rows

typedef __attribute__((ext_vector_type(8))) short bf16x8;   // 8 bf16 in 4 VGPRs
typedef __attribute__((ext_vector_type(4))) float f32x4;

__device__ __forceinline__ unsigned short f2bf(float f) {
  union { float f; unsigned u; } c; c.f = f;
  return (unsigned short)((c.u + 0x7fffu + ((c.u >> 16) & 1u)) >> 16);  // RNE
}

// async global->LDS, 16B per lane; LDS dest must be wave-uniform base + lane*16
__device__ __forceinline__ void gload_lds16(const void* g, void* l) {
  __builtin_amdgcn_global_load_lds((__attribute__((address_space(1))) unsigned int*)g,
                                   (__attribute__((address_space(3))) unsigned int*)l,
                                   16, 0, 0);
}

// XOR swizzle (ushort units) for 16B slots within a 64B row: spreads same-parity
// rows across slots -> <=2-way LDS bank aliasing (free, m136). Applied on the
// GLOBAL source for gload_lds staging (both-sides-or-neither rule) and as an
// address-XOR on direct ds reads/writes. Verified in attn_all (R4 refcheck).
__device__ __forceinline__ int swz8(int row) { return ((row >> 1) & 3) * 8; }

// ---------------- prep kernels ----------------

__global__ __launch_bounds__(256) void conv_bf16(const float* __restrict__ X,
                                                 unsigned short* __restrict__ O, int n) {
  const int i = blockIdx.x * 256 + threadIdx.x;
  const int idx = i * 4;
  if (idx >= n) return;
  const float4 f = *(const float4*)(X + idx);
  ushort4 u; u.x = f2bf(f.x); u.y = f2bf(f.y); u.z = f2bf(f.z); u.w = f2bf(f.w);
  *(ushort4*)(O + idx) = u;
}

// W (K x N fp32, row-major) -> Wt (N x K bf16, row-major)  [B^T layout for gemm]
__global__ __launch_bounds__(256) void trans_conv(const float* __restrict__ W,
                                                  unsigned short* __restrict__ Wt,
                                                  int K, int N) {
  __shared__ float t[32][33];
  const int n0 = blockIdx.x * 32, k0 = blockIdx.y * 32;
  const int tx = threadIdx.x & 31, ty = threadIdx.x >> 5;  // 32 x 8
#pragma unroll
  for (int i = 0; i < 4; ++i)
    t[ty + i * 8][tx] = W[(long)(k0 + ty + i * 8) * N + n0 + tx];
  __syncthreads();
#pragma unroll
  for (int i = 0; i < 4; ++i)
    Wt[(long)(n0 + ty + i * 8) * K + k0 + tx] = f2bf(t[tx][ty + i * 8]);
}

// 4 square DM x DM transposes in one launch (z selects matrix)
__global__ __launch_bounds__(256) void trans_conv4(const float* __restrict__ Wa,
                                                   const float* __restrict__ Wb,
                                                   const float* __restrict__ Wc,
                                                   const float* __restrict__ Wd,
                                                   unsigned short* __restrict__ Oa,
                                                   unsigned short* __restrict__ Ob,
                                                   unsigned short* __restrict__ Oc,
                                                   unsigned short* __restrict__ Od) {
  __shared__ float t[32][33];
  const int z = blockIdx.z;
  const float* W = (z == 0) ? Wa : (z == 1) ? Wb : (z == 2) ? Wc : Wd;
  unsigned short* Wt = (z == 0) ? Oa : (z == 1) ? Ob : (z == 2) ? Oc : Od;
  const int n0 = blockIdx.x * 32, k0 = blockIdx.y * 32;
  const int tx = threadIdx.x & 31, ty = threadIdx.x >> 5;
#pragma unroll
  for (int i = 0; i < 4; ++i)
    t[ty + i * 8][tx] = W[(long)(k0 + ty + i * 8) * DM + n0 + tx];
  __syncthreads();
#pragma unroll
  for (int i = 0; i < 4; ++i)
    Wt[(long)(n0 + ty + i * 8) * DM + k0 + tx] = f2bf(t[tx][ty + i * 8]);
}

__global__ __launch_bounds__(256) void concat3(const float* __restrict__ a,
                                               const float* __restrict__ b,
                                               const float* __restrict__ c,
                                               float* __restrict__ o) {
  const int i = blockIdx.x * 256 + threadIdx.x;  // grid 12 -> 3072
  o[i] = i < 1024 ? a[i] : (i < 2048 ? b[i - 1024] : c[i - 2048]);
}

// ---------------- generic bf16 GEMM: C[m][n] = sum_k A[m][k] * Bt[n][k] ----------------
// BK=32, double-buffered 2-phase prefetch (stage t+1 || compute t, ONE barrier
// per K-step), XOR-swizzled LDS (source-preswizzle + read-XOR -> 2-way banks).
// Per segment LDS: 2 bufs x (A[128][32] + B[128][32]) bf16 = 32 KB.
// EPI: 0 = bf16 store (+bias), 2 = fp32 store + bias + resid,
//      3 = bf16 store of exact GELU(acc + bias), 4 = fused-QKV split epilogue
// KS: in-block split-K (1 or 2); KS=2 -> 512 threads, fp32 combine through LDS.
template <int EPI, int KS>
__global__ __launch_bounds__(256 * KS) void gemm_bt(
    const unsigned short* __restrict__ A, const unsigned short* __restrict__ Bt,
    float* __restrict__ Cf, unsigned short* __restrict__ Cbf,
    const float* __restrict__ bias, const float* __restrict__ resid,
    unsigned short* __restrict__ Vt,
    int M, int N, int K, int lda, int ldb, int ldc) {
  (void)M; (void)N;
  __shared__ unsigned short ldsAB[KS * 16384];  // KS=2 -> 64KB (= fp32 combine buf)

  const int tid = threadIdx.x;
  const int ws = tid >> 8;          // k-segment
  const int t2 = tid & 255;
  const int lane = tid & 63;
  const int w4 = (tid >> 6) & 3;    // wave within segment
  const int quad = lane >> 4, l16 = lane & 15;
  const int wm = (w4 >> 1) * 64, wn = (w4 & 1) * 64;
  const long tileM = (long)blockIdx.x * 128;
  const long tileN = (long)blockIdx.y * 128;

  unsigned short* seg = ldsAB + ws * 16384;   // [buf(2)][A 4096 | B 4096]
  const int kBase = ws * (K / KS);
  const int nt = (K / KS) / 32;

  // per-thread staging addresses (source pre-swizzled to match read-XOR)
  const unsigned short* aS[2];
  const unsigned short* bS[2];
  int dOff[2];
#pragma unroll
  for (int it = 0; it < 2; ++it) {
    const int c = it * 256 + t2;          // 512 chunks of 16B = 8KB tile
    const int row = c >> 2, q = (c & 3) * 8;
    aS[it] = A  + (tileM + row) * (long)lda + kBase + (q ^ swz8(row));
    bS[it] = Bt + (tileN + row) * (long)ldb + kBase + (q ^ swz8(row));
    dOff[it] = c * 8;
  }

  f32x4 acc[4][4];
#pragma unroll
  for (int i = 0; i < 4; ++i)
#pragma unroll
    for (int j = 0; j < 4; ++j)
#pragma unroll
      for (int r = 0; r < 4; ++r) acc[i][j][r] = 0.f;

  // prologue: stage tile 0 into buf 0
#pragma unroll
  for (int it = 0; it < 2; ++it) {
    gload_lds16(aS[it], seg + dOff[it]);
    gload_lds16(bS[it], seg + 4096 + dOff[it]);
  }
  __syncthreads();

  for (int t = 0; t < nt; ++t) {
    unsigned short* cur = seg + (t & 1) * 8192;
    if (t + 1 < nt) {
      unsigned short* nxt = seg + ((t + 1) & 1) * 8192;
      const int ko = (t + 1) * 32;
#pragma unroll
      for (int it = 0; it < 2; ++it) {
        gload_lds16(aS[it] + ko, nxt + dOff[it]);
        gload_lds16(bS[it] + ko, nxt + 4096 + dOff[it]);
      }
    }
    bf16x8 aF[4], bF[4];
#pragma unroll
    for (int i = 0; i < 4; ++i) {
      const int row = wm + i * 16 + l16;
      aF[i] = *(const bf16x8*)&cur[row * 32 + ((quad * 8) ^ swz8(row))];
    }
#pragma unroll
    for (int j = 0; j < 4; ++j) {
      const int row = wn + j * 16 + l16;
      bF[j] = *(const bf16x8*)&cur[4096 + row * 32 + ((quad * 8) ^ swz8(row))];
    }
    __builtin_amdgcn_s_setprio(1);
#pragma unroll
    for (int i = 0; i < 4; ++i)
#pragma unroll
      for (int j = 0; j < 4; ++j)
        acc[i][j] = __builtin_amdgcn_mfma_f32_16x16x32_bf16(aF[i], bF[j], acc[i][j], 0, 0, 0);
    __builtin_amdgcn_s_setprio(0);
    __syncthreads();  // drains t+1 stage loads + all waves' ds_reads of cur
  }

  if constexpr (KS == 2) {
    // final loop barrier already drained everything; LDS reusable as fp32 buf
    float* ldsF = (float*)ldsAB;  // 128x128 fp32 = 64KB
    if (ws == 1) {
#pragma unroll
      for (int i = 0; i < 4; ++i)
#pragma unroll
        for (int j = 0; j < 4; ++j)
#pragma unroll
          for (int r = 0; r < 4; ++r)
            ldsF[(wm + i * 16 + quad * 4 + r) * 128 + wn + j * 16 + l16] = acc[i][j][r];
    }
    __syncthreads();
    if (ws == 1) return;
#pragma unroll
    for (int i = 0; i < 4; ++i)
#pragma unroll
      for (int j = 0; j < 4; ++j)
#pragma unroll
        for (int r = 0; r < 4; ++r)
          acc[i][j][r] += ldsF[(wm + i * 16 + quad * 4 + r) * 128 + wn + j * 16 + l16];
  }

#pragma unroll
  for (int i = 0; i < 4; ++i) {
    const long mb = tileM + wm + i * 16 + quad * 4;
#pragma unroll
    for (int j = 0; j < 4; ++j) {
      const long n = tileN + wn + j * 16 + l16;
      const float bv = bias[n];
      if (EPI == 4) {
        if (n < 2048) {  // Q or K (Kbf is contiguous after Qbf in workspace)
          unsigned short* dst = Cbf + (n >> 10) * ((long)MTOT * DM);
          const int col = (int)n & 1023;
#pragma unroll
          for (int r = 0; r < 4; ++r)
            dst[(mb + r) * DM + col] = f2bf(acc[i][j][r] + bv);
        } else {         // V -> per-head transposed Vt[z][d][s]
          const int nn = (int)n - 2048;
          const int bb2 = (int)(mb >> 11), s = (int)(mb & 2047);
          const int zz = bb2 * 16 + (nn >> 6);
          ushort4 u;
          u.x = f2bf(acc[i][j][0] + bv); u.y = f2bf(acc[i][j][1] + bv);
          u.z = f2bf(acc[i][j][2] + bv); u.w = f2bf(acc[i][j][3] + bv);
          *(ushort4*)&Vt[((long)zz * DKH + (nn & 63)) * SEQ + s] = u;
        }
      } else {
#pragma unroll
        for (int r = 0; r < 4; ++r) {
          const long m = mb + r;
          const long idx = m * ldc + n;
          const float v = acc[i][j][r];
          if (EPI == 0) {
            Cbf[idx] = f2bf(v + bv);
          } else if (EPI == 2) {
            Cf[idx] = v + bv + resid[idx];
          } else {
            const float tt = v + bv;
            Cbf[idx] = f2bf(0.5f * tt * (1.f + erff(tt * 0.70710678118654752f)));
          }
        }
      }
    }
  }
}

// ---------------- merged attention ----------------
// Swapped-operand QK^T: acc[i][j] = mfma(K_frag_j, Q_frag_i) so each lane's 4
// regs are 4 CONSECUTIVE k-cols of ONE q-row (row = wm+i*16+l16, cols =
// wn+j*16+quad*4+r). Enables float4 attn stores, ushort4 P LDS writes, and
// per-row (not per-element-group) online softmax.
// grid (SEQ/128, 1, BATCH*NH), block 256; LDS 80KB -> 2 blocks/CU
__device__ __forceinline__ void stage_k128(const unsigned short* __restrict__ gbase,
                                           unsigned short* lds, int tid) {
#pragma unroll
  for (int it = 0; it < 4; ++it) {
    const int c = it * 256 + tid;
    const int slab = c >> 9, row = (c >> 2) & 127, q = (c & 3) * 8;
    gload_lds16(gbase + (long)row * DM + slab * 32 + (q ^ swz8(row)), lds + c * 8);
  }
}
__device__ __forceinline__ void stage_v64(const unsigned short* __restrict__ gbase,
                                          unsigned short* lds, int tid) {
#pragma unroll
  for (int it = 0; it < 4; ++it) {
    const int c = it * 256 + tid;
    const int slab = c >> 8, row = (c >> 2) & 63, q = (c & 3) * 8;
    gload_lds16(gbase + (long)row * SEQ + slab * 32 + (q ^ swz8(row)), lds + c * 8);
  }
}

__global__ __launch_bounds__(256) void attn_all(const unsigned short* __restrict__ Qbf,
                                                const unsigned short* __restrict__ Kbf,
                                                const unsigned short* __restrict__ Vt,
                                                float* __restrict__ attn,
                                                unsigned short* __restrict__ Ctx) {
  const int z = blockIdx.z, b = z >> 4, h = z & 15;
  const int m0 = blockIdx.x * 128;

  __shared__ unsigned short ldsQ[2 * 128 * 32];  // 16 KB (K dbuf#1 after Q-hoist)
  __shared__ unsigned short ldsK[2 * 128 * 32];  // 16 KB (K dbuf#0)
  __shared__ unsigned short ldsV[4 * 64 * 32];   // 16 KB  [slab][d][32]
  __shared__ unsigned short ldsP[4 * 128 * 32];  // 32 KB  [slab][row][32] (sm alias)

  const int tid = threadIdx.x;
  const int lane = tid & 63, wave = tid >> 6;
  const int quad = lane >> 4, l16 = lane & 15;
  const int wm = (wave >> 1) * 64, wn = (wave & 1) * 64;
  const int wn2 = (wave & 1) * 32;

  const unsigned short* Qbase = Qbf + ((long)(b * SEQ + m0)) * DM + h * DKH;
  const unsigned short* Kz = Kbf + ((long)b * SEQ) * DM + h * DKH;
  const unsigned short* Vz = Vt + (long)z * DKH * SEQ;

  // stage Q strip + K tile 0 (both source-swizzled)
  stage_k128(Qbase, ldsQ, tid);
  stage_k128(Kz, ldsK, tid);
  __syncthreads();

  // hoist Q fragments to registers; ldsQ becomes K double-buffer slot 1
  bf16x8 qF[2][4];
#pragma unroll
  for (int s = 0; s < 2; ++s)
#pragma unroll
    for (int i = 0; i < 4; ++i) {
      const int row = wm + i * 16 + l16;
      qF[s][i] = *(const bf16x8*)&ldsQ[(s * 128 + row) * 32 + ((quad * 8) ^ swz8(row))];
    }
  __syncthreads();

  // ---- sweep 1: per-row online (max, sumexp); lane owns q-row wm+i*16+l16 ----
  float rm[4], rl[4];
#pragma unroll
  for (int i = 0; i < 4; ++i) { rm[i] = -1e30f; rl[i] = 0.f; }

  for (int n = 0; n < 16; ++n) {
    if (n) __syncthreads();
    if (n < 15) stage_k128(Kz + (long)(n + 1) * 128 * DM, (n & 1) ? ldsK : ldsQ, tid);
    const unsigned short* kc = (n & 1) ? ldsQ : ldsK;

    f32x4 acc[4][4];
#pragma unroll
    for (int i = 0; i < 4; ++i)
#pragma unroll
      for (int j = 0; j < 4; ++j)
#pragma unroll
        for (int r = 0; r < 4; ++r) acc[i][j][r] = 0.f;
    __builtin_amdgcn_s_setprio(1);
#pragma unroll
    for (int s = 0; s < 2; ++s) {
      bf16x8 bF[4];
#pragma unroll
      for (int j = 0; j < 4; ++j) {
        const int row = wn + j * 16 + l16;
        bF[j] = *(const bf16x8*)&kc[(s * 128 + row) * 32 + ((quad * 8) ^ swz8(row))];
      }
#pragma unroll
      for (int i = 0; i < 4; ++i)
#pragma unroll
        for (int j = 0; j < 4; ++j)
          acc[i][j] = __builtin_amdgcn_mfma_f32_16x16x32_bf16(bF[j], qF[s][i], acc[i][j], 0, 0, 0);
    }
    __builtin_amdgcn_s_setprio(0);

#pragma unroll
    for (int i = 0; i < 4; ++i) {
      float tm = acc[i][0][0];
#pragma unroll
      for (int j = 0; j < 4; ++j)
#pragma unroll
        for (int r = 0; r < 4; ++r) tm = fmaxf(tm, acc[i][j][r]);
      const float tms = tm * 0.125f;
      const float mn = fmaxf(rm[i], tms);
      float sum = 0.f;
#pragma unroll
      for (int j = 0; j < 4; ++j)
#pragma unroll
        for (int r = 0; r < 4; ++r)
          sum += __expf(fmaf(acc[i][j][r], 0.125f, -mn));
      rl[i] = rl[i] * __expf(rm[i] - mn) + sum;
      rm[i] = mn;
    }
  }

  // merge across the 4 quads (same q-row, disjoint k-chunks): 2 butterfly steps
#pragma unroll
  for (int i = 0; i < 4; ++i) {
    float m = rm[i], l = rl[i];
#pragma unroll
    for (int o = 16; o < 64; o <<= 1) {
      const float om = __shfl_xor(m, o), ol = __shfl_xor(l, o);
      const float mn = fmaxf(m, om);
      l = l * __expf(m - mn) + ol * __expf(om - mn);
      m = mn;
    }
    rm[i] = m; rl[i] = l;
  }

  // combine the two wn-halves per row through LDS (alias head of ldsP)
  float2* sm = (float2*)ldsP;
  if (quad == 0) {
#pragma unroll
    for (int i = 0; i < 4; ++i)
      sm[wave * 64 + i * 16 + l16] = make_float2(rm[i], rl[i]);
  }
  __syncthreads();
  float sM[4], sI[4];
#pragma unroll
  for (int i = 0; i < 4; ++i) {
    const int rr = i * 16 + l16;
    const float2 A = sm[(wave & ~1) * 64 + rr];
    const float2 B = sm[((wave & ~1) + 1) * 64 + rr];
    const float M = fmaxf(A.x, B.x);
    const float Z = A.y * __expf(A.x - M) + B.y * __expf(B.x - M);
    sM[i] = M; sI[i] = 1.f / Z;
  }

  // ---- sweep 2: P write + PV ----
  f32x4 acc_o[4][2];
#pragma unroll
  for (int i = 0; i < 4; ++i)
#pragma unroll
    for (int j = 0; j < 2; ++j)
#pragma unroll
      for (int r = 0; r < 4; ++r) acc_o[i][j][r] = 0.f;

  stage_k128(Kz, ldsK, tid);  // restage tile 0
  __syncthreads();            // sm reads done by all waves + K0 staged

  for (int n = 0; n < 16; ++n) {
    if (n) __syncthreads();   // [A] prior PV reads of ldsP/ldsV done
    if (n < 15) stage_k128(Kz + (long)(n + 1) * 128 * DM, (n & 1) ? ldsK : ldsQ, tid);
    stage_v64(Vz + n * 128, ldsV, tid);
    const unsigned short* kc = (n & 1) ? ldsQ : ldsK;

    f32x4 acc[4][4];
#pragma unroll
    for (int i = 0; i < 4; ++i)
#pragma unroll
      for (int j = 0; j < 4; ++j)
#pragma unroll
        for (int r = 0; r < 4; ++r) acc[i][j][r] = 0.f;
    __builtin_amdgcn_s_setprio(1);
#pragma unroll
    for (int s = 0; s < 2; ++s) {
      bf16x8 bF[4];
#pragma unroll
      for (int j = 0; j < 4; ++j) {
        const int row = wn + j * 16 + l16;
        bF[j] = *(const bf16x8*)&kc[(s * 128 + row) * 32 + ((quad * 8) ^ swz8(row))];
      }
#pragma unroll
      for (int i = 0; i < 4; ++i)
#pragma unroll
        for (int j = 0; j < 4; ++j)
          acc[i][j] = __builtin_amdgcn_mfma_f32_16x16x32_bf16(bF[j], qF[s][i], acc[i][j], 0, 0, 0);
    }
    __builtin_amdgcn_s_setprio(0);

    // P = exp(S/8 - M) * invZ : f32x4 nt store to attn + ushort4 into ldsP
    float* attnBase = attn + (long)z * SEQ * SEQ + (long)m0 * SEQ + n * 128;
#pragma unroll
    for (int i = 0; i < 4; ++i) {
      const int rowl = wm + i * 16 + l16;
      const float M = sM[i], I = sI[i];
#pragma unroll
      for (int j = 0; j < 4; ++j) {
        const int col = wn + j * 16 + quad * 4;
        f32x4 p4;
        p4[0] = __expf(fmaf(acc[i][j][0], 0.125f, -M)) * I;
        p4[1] = __expf(fmaf(acc[i][j][1], 0.125f, -M)) * I;
        p4[2] = __expf(fmaf(acc[i][j][2], 0.125f, -M)) * I;
        p4[3] = __expf(fmaf(acc[i][j][3], 0.125f, -M)) * I;
        __builtin_nontemporal_store(p4, (f32x4*)(attnBase + (long)rowl * SEQ + col));
        ushort4 u;
        u.x = f2bf(p4[0]); u.y = f2bf(p4[1]); u.z = f2bf(p4[2]); u.w = f2bf(p4[3]);
        const int uoff = ((col >> 5) * 128 + rowl) * 32 + ((col & 31) ^ swz8(rowl));
        *(ushort4*)&ldsP[uoff] = u;
      }
    }
    __syncthreads();  // [B] P visible; V(n)/K(n+1) gloads drained

    __builtin_amdgcn_s_setprio(1);
#pragma unroll
    for (int slab = 0; slab < 4; ++slab) {
      bf16x8 aF[4], bF[2];
#pragma unroll
      for (int i = 0; i < 4; ++i) {
        const int row = wm + i * 16 + l16;
        aF[i] = *(const bf16x8*)&ldsP[(slab * 128 + row) * 32 + ((quad * 8) ^ swz8(row))];
      }
#pragma unroll
      for (int j = 0; j < 2; ++j) {
        const int d = wn2 + j * 16 + l16;
        bF[j] = *(const bf16x8*)&ldsV[(slab * 64 + d) * 32 + ((quad * 8) ^ swz8(d))];
      }
#pragma unroll
      for (int i = 0; i < 4; ++i)
#pragma unroll
        for (int j = 0; j < 2; ++j)
          acc_o[i][j] = __builtin_amdgcn_mfma_f32_16x16x32_bf16(aF[i], bF[j], acc_o[i][j], 0, 0, 0);
    }
    __builtin_amdgcn_s_setprio(0);
  }

  // epilogue: ctx bf16 (rows interleaved back to [B*S][DM])
#pragma unroll
  for (int i = 0; i < 4; ++i)
#pragma unroll
    for (int j = 0; j < 2; ++j) {
      const int d = h * DKH + wn2 + j * 16 + l16;
#pragma unroll
      for (int r = 0; r < 4; ++r) {
        const long m = (long)b * SEQ + m0 + wm + i * 16 + quad * 4 + r;
        Ctx[m * DM + d] = f2bf(acc_o[i][j][r]);
      }
    }
}

// ---------------- LayerNorm over rows of 1024 ----------------
__global__ __launch_bounds__(256) void layernorm_row(const float* __restrict__ Y,
                                                     const float* __restrict__ g,
                                                     const float* __restrict__ bb,
                                                     float* __restrict__ outF,
                                                     unsigned short* __restrict__ outBf) {
  const long row = blockIdx.x;
  const float* p = Y + row * DM;
  const int tid = threadIdx.x;
  const float4 v = *(const float4*)(p + tid * 4);
  float s = v.x + v.y + v.z + v.w;
  float ss = v.x * v.x + v.y * v.y + v.z * v.z + v.w * v.w;
#pragma unroll
  for (int o = 32; o > 0; o >>= 1) { s += __shfl_xor(s, o); ss += __shfl_xor(ss, o); }
  __shared__ float rs[4], rss[4];
  if ((tid & 63) == 0) { rs[tid >> 6] = s; rss[tid >> 6] = ss; }
  __syncthreads();
  s = rs[0] + rs[1] + rs[2] + rs[3];
  ss = rss[0] + rss[1] + rss[2] + rss[3];
  const float mu = s * (1.f / DM);
  const float var = ss * (1.f / DM) - mu * mu;
  const float rstd = rsqrtf(var + 1e-5f);
  const float4 gv = *(const float4*)(g + tid * 4);
  const float4 bv = *(const float4*)(bb + tid * 4);
  float4 o;
  o.x = (v.x - mu) * rstd * gv.x + bv.x;
  o.y = (v.y - mu) * rstd * gv.y + bv.y;
  o.z = (v.z - mu) * rstd * gv.z + bv.z;
  o.w = (v.w - mu) * rstd * gv.w + bv.w;
  *(float4*)(outF + row * DM + tid * 4) = o;
  if (outBf) {
    ushort4 u; u.x = f2bf(o.x); u.y = f2bf(o.y); u.z = f2bf(o.z); u.w = f2bf(o.w);
    *(ushort4*)(outBf + row * DM + tid * 4) = u;
  }
}

// ---------------- launch ----------------
extern "C" void kernel_launch(void* const* d_in, const int* in_sizes, int n_in,
                              void* d_out, int out_size, void* d_ws, size_t ws_size,
                              hipStream_t stream) {
  (void)in_sizes; (void)n_in; (void)out_size; (void)ws_size;
  const float* x  = (const float*)d_in[0];
  const float* Wq = (const float*)d_in[1];
  const float* bq = (const float*)d_in[2];
  const float* Wk = (const float*)d_in[3];
  const float* bk = (const float*)d_in[4];
  const float* Wv = (const float*)d_in[5];
  const float* bv = (const float*)d_in[6];
  const float* Wo = (const float*)d_in[7];
  const float* bo = (const float*)d_in[8];
  const float* g1 = (const float*)d_in[9];
  const float* b1 = (const float*)d_in[10];
  const float* W1 = (const float*)d_in[11];
  const float* bf1 = (const float*)d_in[12];
  const float* W2 = (const float*)d_in[13];
  const float* bf2 = (const float*)d_in[14];
  const float* g2 = (const float*)d_in[15];
  const float* b2 = (const float*)d_in[16];

  float* out  = (float*)d_out;
  float* attn = out + (long)MTOT * DM;   // (B,H,S,S) fp32 — written once, by attn_all

  // workspace layout (liveness-aliased), 96 MB total
  char* w = (char*)d_ws;
  const long MB = 1024L * 1024L;
  unsigned short* Wqkvt = (unsigned short*)(w + 0 * MB);   // 6 MB [Wq|Wk|Wv]^T
  unsigned short* Wot   = (unsigned short*)(w + 6 * MB);   // 2 MB
  unsigned short* W1t   = (unsigned short*)(w + 8 * MB);   // 8 MB
  unsigned short* W2t   = (unsigned short*)(w + 16 * MB);  // 8 MB
  unsigned short* xbf   = (unsigned short*)(w + 24 * MB);  // 8 MB, reused as hbf
  unsigned short* hbf   = xbf;
  unsigned short* Qbf   = (unsigned short*)(w + 32 * MB);  // 8 MB ┐ Kbf MUST follow Qbf
  unsigned short* Kbf   = (unsigned short*)(w + 40 * MB);  // 8 MB │ (EPI4 relies on it)
  unsigned short* Vt    = (unsigned short*)(w + 48 * MB);  // 8 MB │ ffbf aliases 32..64 MB
  unsigned short* ctxbf = (unsigned short*)(w + 56 * MB);  // 8 MB ┘
  unsigned short* ffbf  = Qbf;                             // 32 MB alias (dead by FF1)
  float* bqkv = (float*)(w + 64 * MB);                     // 12 KB, dead before y written
  float* y    = (float*)(w + 64 * MB);                     // 16 MB (first write: Wo-gemm)
  float* h    = (float*)(w + 80 * MB);                     // 16 MB

  const dim3 blk(256), blk2(512);

  // prep
  conv_bf16<<<dim3(MTOT * DM / 1024), blk, 0, stream>>>(x, xbf, MTOT * DM);
  trans_conv4<<<dim3(DM / 32, DM / 32, 4), blk, 0, stream>>>(
      Wq, Wk, Wv, Wo, Wqkvt, Wqkvt + 1024 * 1024, Wqkvt + 2 * 1024 * 1024, Wot);
  trans_conv<<<dim3(DFF / 32, DM / 32), blk, 0, stream>>>(W1, W1t, DM, DFF);
  trans_conv<<<dim3(DM / 32, DFF / 32), blk, 0, stream>>>(W2, W2t, DFF, DM);
  concat3<<<dim3(12), blk, 0, stream>>>(bq, bk, bv, bqkv);

  // fused QKV projection: N=3072, V written directly per-head-transposed
  gemm_bt<4, 1><<<dim3(MTOT / 128, 3072 / 128), blk, 0, stream>>>(
      xbf, Wqkvt, nullptr, Qbf, bqkv, nullptr, Vt, MTOT, 3072, DM, DM, DM, DM);

  // merged attention (stats sweep + P-write + PV)
  attn_all<<<dim3(SEQ / 128, 1, BATCH * NH), blk, 0, stream>>>(Qbf, Kbf, Vt, attn, ctxbf);

  // attn_out = ctx @ Wo + bo + x  (fp32); split-K for occupancy
  gemm_bt<2, 2><<<dim3(MTOT / 128, DM / 128), blk2, 0, stream>>>(
      ctxbf, Wot, y, nullptr, bo, x, nullptr, MTOT, DM, DM, DM, DM, DM);
  layernorm_row<<<dim3(MTOT), blk, 0, stream>>>(y, g1, b1, h, hbf);

  // FFN
  gemm_bt<3, 1><<<dim3(MTOT / 128, DFF / 128), blk, 0, stream>>>(
      hbf, W1t, nullptr, ffbf, bf1, nullptr, nullptr, MTOT, DFF, DM, DM, DM, DFF);
  gemm_bt<2, 2><<<dim3(MTOT / 128, DM / 128), blk2, 0, stream>>>(
      ffbf, W2t, y, nullptr, bf2, h, nullptr, MTOT, DM, DFF, DFF, DFF, DM);
  layernorm_row<<<dim3(MTOT), blk, 0, stream>>>(y, g2, b2, out, nullptr);
}